// Round 3
// baseline (85.510 us; speedup 1.0000x reference)
//
#include <hip/hip_runtime.h>
#include <hip/hip_fp16.h>

// NonAutoregressiveDecoder: K=1024, H=128, fp32 I/O.
// out = (coords_pred [1024,2], adj_logits [1024,1024]) flat-concat.

#define KN 1024
#define HN 128

typedef float  floatx4 __attribute__((ext_vector_type(4)));
typedef float  floatx2 __attribute__((ext_vector_type(2)));
typedef _Float16 half8v __attribute__((ext_vector_type(8)));
typedef _Float16 half2v __attribute__((ext_vector_type(2)));

// Transcendental-free GELU: gelu(x) = 0.5*t + t^2 * u(t^2), t = clamp(x,-4,4),
// u(s) = degree-5 poly (erf-based weighted fit on s in [0,13.7], err(gelu) <~ 1e-3).
#define GA0 0.398707f
#define GA1 (-0.065235f)
#define GA2 0.0088204f
#define GA3 (-0.00076934f)
#define GA4 0.0000375046f
#define GA5 (-0.00000076344f)

__device__ __forceinline__ float gelu_f(float x) {
    float t = __builtin_amdgcn_fmed3f(x, -4.0f, 4.0f);   // clamp, 1 inst
    float s = t * t;
    float u = fmaf(s, GA5, GA4);
    u = fmaf(s, u, GA3);
    u = fmaf(s, u, GA2);
    u = fmaf(s, u, GA1);
    u = fmaf(s, u, GA0);
    return fmaf(s, u, 0.5f * t);
}

// packed GELU on 2 f16 elements held in a uint; clamp + poly evaluated in f32
// pairs (float2 fma can form v_pk_fma_f32; scalar f32 fallback still fine).
__device__ __forceinline__ unsigned int gelu2u(unsigned int xu) {
    half2v x = __builtin_bit_cast(half2v, xu);
    floatx2 t = { __builtin_amdgcn_fmed3f((float)x[0], -4.0f, 4.0f),
                  __builtin_amdgcn_fmed3f((float)x[1], -4.0f, 4.0f) };
    floatx2 s = t * t;
    floatx2 u = __builtin_elementwise_fma(s, (floatx2)(GA5), (floatx2)(GA4));
    u = __builtin_elementwise_fma(s, u, (floatx2)(GA3));
    u = __builtin_elementwise_fma(s, u, (floatx2)(GA2));
    u = __builtin_elementwise_fma(s, u, (floatx2)(GA1));
    u = __builtin_elementwise_fma(s, u, (floatx2)(GA0));
    floatx2 r = __builtin_elementwise_fma(s, u, 0.5f * t);
    return __builtin_bit_cast(unsigned int,
                              __builtin_amdgcn_cvt_pkrtz(r[0], r[1]));
}

// ---------------- Kernel A: pi' = z@eW1[:H]+eb1 (f16), pj = z@eW1[H:] (f16),
//                  coords -> d_out, w2T (f16 transpose of eW2) -------------
__global__ __launch_bounds__(256) void prep_kernel(
    const float* __restrict__ z,   const float* __restrict__ cW1,
    const float* __restrict__ cb1, const float* __restrict__ cW2,
    const float* __restrict__ cb2, const float* __restrict__ eW1,
    const float* __restrict__ eb1, const float* __restrict__ eW2,
    _Float16* __restrict__ pi_h,   _Float16* __restrict__ pj_h,
    _Float16* __restrict__ w2T,    float* __restrict__ coords /* = d_out */) {
    __shared__ float z8[8][128];
    __shared__ float c1s[8][64];
    const int tid = threadIdx.x;
    const int r0  = blockIdx.x * 8;

    // w2T fill: blocks 0..31, 256 elems each. w2T[col][k] = eW2[k][col]
    if (blockIdx.x < 32) {
        int e = blockIdx.x * 256 + tid;          // e = col*128 + k
        w2T[e] = (_Float16)eW2[(e & 127) * 64 + (e >> 7)];
    }

#pragma unroll
    for (int s = 0; s < 4; ++s) {
        int e = tid + 256 * s;
        z8[e >> 7][e & 127] = z[r0 * HN + e];
    }
    __syncthreads();

    const int col = tid & 127, which = tid >> 7;
    const float* w = eW1 + which * HN * HN + col;
    float acc8[8] = {0.f, 0.f, 0.f, 0.f, 0.f, 0.f, 0.f, 0.f};
    for (int k = 0; k < HN; ++k) {
        float wv = w[k * HN];
#pragma unroll
        for (int r = 0; r < 8; ++r) acc8[r] = fmaf(z8[r][k], wv, acc8[r]);
    }
    if (which == 0) {
        float b = eb1[col];
#pragma unroll
        for (int r = 0; r < 8; ++r)
            pi_h[(r0 + r) * HN + col] = (_Float16)(acc8[r] + b);
    } else {
#pragma unroll
        for (int r = 0; r < 8; ++r)
            pj_h[(r0 + r) * HN + col] = (_Float16)acc8[r];
    }

    // coords: c1 = gelu(z @ cW1 + cb1), coords = c1 @ cW2 + cb2
#pragma unroll
    for (int s = 0; s < 2; ++s) {
        int task = tid + 256 * s;          // 512 tasks = 8 rows x 64 mids
        int row = task >> 6, mid = task & 63;
        float a = cb1[mid];
        for (int k = 0; k < HN; ++k) a = fmaf(z8[row][k], cW1[k * 64 + mid], a);
        c1s[row][mid] = gelu_f(a);
    }
    __syncthreads();
    if (tid < 16) {
        int row = tid >> 1, o = tid & 1;
        float a = cb2[o];
#pragma unroll 8
        for (int m = 0; m < 64; ++m) a = fmaf(c1s[row][m], cW2[m * 2 + o], a);
        coords[(r0 + row) * 2 + o] = a;
    }
}

// ---------------- Kernel B: fused h1->h2->adj_raw over a 32x16 (i,j) tile ----
// 512 threads (8 waves), each wave does 4 i-rows. w2 fragments live in LDS;
// all LDS buffers XOR-swizzled: dword_idx ^= (row&7)<<2.
__global__ __launch_bounds__(512, 7) void edge_kernel(
    const _Float16* __restrict__ pi_h, const _Float16* __restrict__ pj_h,
    const _Float16* __restrict__ w2T,  const float* __restrict__ eb2,
    const float* __restrict__ eW3,     const float* __restrict__ eb3,
    float* __restrict__ out_adj) {
    __shared__ __align__(16) unsigned int pi_s[32 * 64];  // 8 KB  [32 rows][64 dw]
    __shared__ __align__(16) unsigned int pj_s[16 * 64];  // 4 KB  [16 rows][64 dw]
    __shared__ __align__(16) unsigned int w2_s[64 * 64];  // 16 KB [64 dims][64 dw]
    const int i0 = blockIdx.y * 32, j0 = blockIdx.x * 16;
    const int tid = threadIdx.x;

    const unsigned int* piu = (const unsigned int*)pi_h;   // [1024][64]
    const unsigned int* pju = (const unsigned int*)pj_h;
    const unsigned int* w2u = (const unsigned int*)w2T;    // [64][64]

#pragma unroll
    for (int s = 0; s < 4; ++s) {
        int e = tid + 512 * s;            // 0..2047
        int r = e >> 6;
        pi_s[e ^ ((r & 7) << 2)] = piu[(i0 + r) * 64 + (e & 63)];
    }
#pragma unroll
    for (int s = 0; s < 2; ++s) {
        int e = tid + 512 * s;            // 0..1023
        int r = e >> 6;
        pj_s[e ^ ((r & 7) << 2)] = pju[(j0 + r) * 64 + (e & 63)];
    }
#pragma unroll
    for (int s = 0; s < 8; ++s) {
        int e = tid + 512 * s;            // 0..4095
        int r = e >> 6;
        w2_s[e ^ ((r & 7) << 2)] = w2u[e];
    }

    const int lane = tid & 63;
    const int wave = tid >> 6;          // 0..7
    const int lrow = lane & 15;         // A-row (j) / B-col (h2 dim) within 16
    const int lhi  = lane >> 4;         // k-block / C-row-group
    const int lhi4 = lhi << 2;
    const int swzJ = (lrow & 7) << 2;

    const unsigned int* pjrow  = &pj_s[lrow << 6];
    const unsigned int* w2base = &w2_s[lrow << 6];

    float eb2_l[4], w3_l[4];
#pragma unroll
    for (int c = 0; c < 4; ++c) {
        eb2_l[c] = eb2[c * 16 + lrow];
        w3_l[c]  = eW3[c * 16 + lrow];
    }
    const float b3 = eb3[0];
    __syncthreads();

#pragma unroll
    for (int t = 0; t < 4; ++t) {
        const int iL = (wave << 2) + t;             // 0..31
        const unsigned int* pirow = &pi_s[iL << 6];
        const int swzI = (iL & 7) << 2;

        floatx4 acc[4];
#pragma unroll
        for (int c = 0; c < 4; ++c) acc[c] = (floatx4){0.f, 0.f, 0.f, 0.f};

#pragma unroll
        for (int q = 0; q < 4; ++q) {
            const int ko = (q << 4) + lhi4;         // dword offset within row
            half8v a = *reinterpret_cast<const half8v*>(&pirow[ko ^ swzI]);
            half8v b = *reinterpret_cast<const half8v*>(&pjrow[ko ^ swzJ]);
            uint4 su = __builtin_bit_cast(uint4, a + b);   // v_pk_add_f16
            uint4 gu;
            gu.x = gelu2u(su.x);
            gu.y = gelu2u(su.y);
            gu.z = gelu2u(su.z);
            gu.w = gelu2u(su.w);
            half8v af = __builtin_bit_cast(half8v, gu);
            const int kw = ko ^ swzJ;               // w2 rows share lrow&7 swizzle
#pragma unroll
            for (int c = 0; c < 4; ++c) {
                half8v bf = *reinterpret_cast<const half8v*>(
                    &w2base[(c << 10) + kw]);       // row c*16+lrow, same offset
                acc[c] = __builtin_amdgcn_mfma_f32_16x16x32_f16(
                    af, bf, acc[c], 0, 0, 0);
            }
        }

        // epilogue: h2 = gelu(acc + eb2); adj = h2 . eW3 + eb3
        float tv[4];
#pragma unroll
        for (int m = 0; m < 4; ++m) {
            float s = 0.f;
#pragma unroll
            for (int c = 0; c < 4; ++c)
                s = fmaf(gelu_f(acc[c][m] + eb2_l[c]), w3_l[c], s);
            s += __shfl_xor(s, 1);
            s += __shfl_xor(s, 2);
            s += __shfl_xor(s, 4);
            s += __shfl_xor(s, 8);
            tv[m] = s + b3;
        }
        if (lrow == 0) {
            float4 v = make_float4(tv[0], tv[1], tv[2], tv[3]);
            *reinterpret_cast<float4*>(
                &out_adj[(size_t)(i0 + iL) * KN + j0 + lhi4]) = v;
        }
    }
}

// ---------------- Kernel C: in-place symmetrize ------------------------------
__global__ __launch_bounds__(256) void sym_kernel(float* __restrict__ adj) {
    int idx = blockIdx.x * 256 + threadIdx.x;
    int i = idx >> 10, j = idx & 1023;
    if (j < i) return;
    float a = adj[i * KN + j];
    float b = adj[j * KN + i];
    float m = 0.5f * (a + b);
    adj[i * KN + j] = m;
    adj[j * KN + i] = m;
}

extern "C" void kernel_launch(void* const* d_in, const int* in_sizes, int n_in,
                              void* d_out, int out_size, void* d_ws, size_t ws_size,
                              hipStream_t stream) {
    const float* z   = (const float*)d_in[0];
    const float* cW1 = (const float*)d_in[1];
    const float* cb1 = (const float*)d_in[2];
    const float* cW2 = (const float*)d_in[3];
    const float* cb2 = (const float*)d_in[4];
    const float* eW1 = (const float*)d_in[5];
    const float* eb1 = (const float*)d_in[6];
    const float* eW2 = (const float*)d_in[7];
    const float* eb2 = (const float*)d_in[8];
    const float* eW3 = (const float*)d_in[9];
    const float* eb3 = (const float*)d_in[10];

    float* out = (float*)d_out;
    _Float16* pi_h = (_Float16*)d_ws;            // [1024][128] f16
    _Float16* pj_h = pi_h + KN * HN;             // [1024][128] f16
    _Float16* w2T  = pj_h + KN * HN;             // [64][128]  f16 (eW2^T)

    prep_kernel<<<128, 256, 0, stream>>>(z, cW1, cb1, cW2, cb2, eW1, eb1, eW2,
                                         pi_h, pj_h, w2T, out);

    dim3 gridB(64, 32);   // x: 16-wide j tiles, y: 32-tall i tiles
    edge_kernel<<<gridB, 512, 0, stream>>>(pi_h, pj_h, w2T, eb2, eW3, eb3,
                                           out + 2048);

    sym_kernel<<<4096, 256, 0, stream>>>(out + 2048);
}

// Round 4
// 79.483 us; speedup vs baseline: 1.0758x; 1.0758x over previous
//
#include <hip/hip_runtime.h>
#include <hip/hip_fp16.h>

// NonAutoregressiveDecoder: K=1024, H=128, fp32 I/O.
// out = (coords_pred [1024,2], adj_logits [1024,1024]) flat-concat.

#define KN 1024
#define HN 128

typedef float  floatx4 __attribute__((ext_vector_type(4)));
typedef _Float16 half8v __attribute__((ext_vector_type(8)));
typedef _Float16 half2v __attribute__((ext_vector_type(2)));

// f32 GELU (tanh form, log2e folded): x / (1 + exp2(x*(-2.3022087 - 0.1029434 x^2)))
__device__ __forceinline__ float gelu_f(float x) {
    float x2 = x * x;
    float t  = fmaf(x2, -0.1029434f, -2.3022087f);
    float e  = __builtin_amdgcn_exp2f(x * t);
    return x * __builtin_amdgcn_rcpf(e + 1.0f);
}

// packed-f16 GELU on 2 elements held in a uint (exp2/rcp are ~full-rate on gfx950)
__device__ __forceinline__ unsigned int gelu2u(unsigned int xu) {
    __half2 x  = __builtin_bit_cast(__half2, xu);
    __half2 x2 = __hmul2(x, x);
    __half2 t  = __hfma2(x2, __float2half2_rn(-0.1029434f),
                             __float2half2_rn(-2.3022087f));
    __half2 e  = h2exp2(__hmul2(x, t));
    __half2 r  = h2rcp(__hadd2(e, __float2half2_rn(1.0f)));
    return __builtin_bit_cast(unsigned int, __hmul2(x, r));
}

__device__ __forceinline__ unsigned int cvt2u(float a, float b) {
    return __builtin_bit_cast(unsigned int, __builtin_amdgcn_cvt_pkrtz(a, b));
}

// ---------------- Kernel A: pi' = z@eW1[:H]+eb1 (f16), pj = z@eW1[H:] (f16),
//   coords -> d_out, w2T (f16, dim-PERMUTED transpose of eW2), w3h (f16 eW3) --
// w2T storage row R(d) places dim d so that the edge kernel's dot-MFMA needs
// no cross-lane shuffles: R(d) = 32*(d>>5) + 16*((d>>2)&1) + 4*((d>>3)&3) + (d&3).
__global__ __launch_bounds__(256) void prep_kernel(
    const float* __restrict__ z,   const float* __restrict__ cW1,
    const float* __restrict__ cb1, const float* __restrict__ cW2,
    const float* __restrict__ cb2, const float* __restrict__ eW1,
    const float* __restrict__ eb1, const float* __restrict__ eW2,
    const float* __restrict__ eW3,
    _Float16* __restrict__ pi_h,   _Float16* __restrict__ pj_h,
    _Float16* __restrict__ w2T,    _Float16* __restrict__ w3h,
    float* __restrict__ coords /* = d_out */) {
    __shared__ float z8[8][128];
    __shared__ float c1s[8][64];
    const int tid = threadIdx.x;
    const int r0  = blockIdx.x * 8;

    // w2T fill (permuted rows): blocks 0..31, 256 elems each.
    if (blockIdx.x < 32) {
        int e = blockIdx.x * 256 + tid;          // e = d*128 + k
        int d = e >> 7, k = e & 127;
        int R = ((d >> 5) & 1) * 32 + ((d >> 2) & 1) * 16 +
                ((d >> 3) & 3) * 4  + (d & 3);
        w2T[R * 128 + k] = (_Float16)eW2[k * 64 + d];
    }
    if (blockIdx.x == 32 && tid < 64) w3h[tid] = (_Float16)eW3[tid];

#pragma unroll
    for (int s = 0; s < 4; ++s) {
        int e = tid + 256 * s;
        z8[e >> 7][e & 127] = z[r0 * HN + e];
    }
    __syncthreads();

    const int col = tid & 127, which = tid >> 7;
    const float* w = eW1 + which * HN * HN + col;
    float acc8[8] = {0.f, 0.f, 0.f, 0.f, 0.f, 0.f, 0.f, 0.f};
    for (int k = 0; k < HN; ++k) {
        float wv = w[k * HN];
#pragma unroll
        for (int r = 0; r < 8; ++r) acc8[r] = fmaf(z8[r][k], wv, acc8[r]);
    }
    if (which == 0) {
        float b = eb1[col];
#pragma unroll
        for (int r = 0; r < 8; ++r)
            pi_h[(r0 + r) * HN + col] = (_Float16)(acc8[r] + b);
    } else {
#pragma unroll
        for (int r = 0; r < 8; ++r)
            pj_h[(r0 + r) * HN + col] = (_Float16)acc8[r];
    }

    // coords: c1 = gelu(z @ cW1 + cb1), coords = c1 @ cW2 + cb2
#pragma unroll
    for (int s = 0; s < 2; ++s) {
        int task = tid + 256 * s;          // 512 tasks = 8 rows x 64 mids
        int row = task >> 6, mid = task & 63;
        float a = cb1[mid];
        for (int k = 0; k < HN; ++k) a = fmaf(z8[row][k], cW1[k * 64 + mid], a);
        c1s[row][mid] = gelu_f(a);
    }
    __syncthreads();
    if (tid < 16) {
        int row = tid >> 1, o = tid & 1;
        float a = cb2[o];
#pragma unroll 8
        for (int m = 0; m < 64; ++m) a = fmaf(c1s[row][m], cW2[m * 2 + o], a);
        coords[(r0 + row) * 2 + o] = a;
    }
}

// ---------------- Kernel B: fused h1->h2->adj_raw over a 32x16 (i,j) tile ----
// 512 threads (8 waves), each wave does 4 i-rows. Main MFMA computes C^T
// (A = w2 rows, B = h1), so lane's acc holds h2 at (dim-slot, j=lrow); the
// w3 dot is then a second MFMA (A = w3 broadcast rows) — no shuffles.
// Bias eb2 folds into acc init; eb3 into the dot-MFMA C init.
__global__ __launch_bounds__(512, 7) void edge_kernel(
    const _Float16* __restrict__ pi_h, const _Float16* __restrict__ pj_h,
    const _Float16* __restrict__ w2T,  const _Float16* __restrict__ w3h,
    const float* __restrict__ eb2,     const float* __restrict__ eb3,
    float* __restrict__ out_adj) {
    __shared__ __align__(16) unsigned int pi_s[32 * 64];  // 8 KB  [32 rows][64 dw]
    __shared__ __align__(16) unsigned int pj_s[16 * 64];  // 4 KB  [16 rows][64 dw]
    __shared__ __align__(16) unsigned int w2_s[64 * 64];  // 16 KB [64 slots][64 dw]
    const int i0 = blockIdx.y * 32, j0 = blockIdx.x * 16;
    const int tid = threadIdx.x;

    const unsigned int* piu = (const unsigned int*)pi_h;   // [1024][64]
    const unsigned int* pju = (const unsigned int*)pj_h;
    const unsigned int* w2u = (const unsigned int*)w2T;    // [64][64]

#pragma unroll
    for (int s = 0; s < 4; ++s) {
        int e = tid + 512 * s;            // 0..2047
        int r = e >> 6;
        pi_s[e ^ ((r & 7) << 2)] = piu[(i0 + r) * 64 + (e & 63)];
    }
#pragma unroll
    for (int s = 0; s < 2; ++s) {
        int e = tid + 512 * s;            // 0..1023
        int r = e >> 6;
        pj_s[e ^ ((r & 7) << 2)] = pju[(j0 + r) * 64 + (e & 63)];
    }
#pragma unroll
    for (int s = 0; s < 8; ++s) {
        int e = tid + 512 * s;            // 0..4095
        int r = e >> 6;
        w2_s[e ^ ((r & 7) << 2)] = w2u[e];
    }

    const int lane = tid & 63;
    const int wave = tid >> 6;          // 0..7
    const int lrow = lane & 15;         // j within tile / MFMA col
    const int lhi  = lane >> 4;         // k-slice group
    const int lhi4 = lhi << 2;
    const int lhi8 = lhi << 3;
    const int swzJ = (lrow & 7) << 2;

    const unsigned int* pjrow  = &pj_s[lrow << 6];
    const unsigned int* w2base = &w2_s[lrow << 6];

    // w3 A-fragments (uniform over lrow): a[e] = w3[k], k = lhi*8+e (+32)
    const half8v w3f0 = *reinterpret_cast<const half8v*>(&w3h[lhi8]);
    const half8v w3f1 = *reinterpret_cast<const half8v*>(&w3h[32 + lhi8]);
    // eb2 at permuted slots: acc[c][m] = eb2[32*(c>>1) + 8*lhi + 4*(c&1) + m]
    const float4 e0 = *reinterpret_cast<const float4*>(&eb2[lhi8]);
    const float4 e1 = *reinterpret_cast<const float4*>(&eb2[lhi8 + 4]);
    const float4 e2 = *reinterpret_cast<const float4*>(&eb2[32 + lhi8]);
    const float4 e3 = *reinterpret_cast<const float4*>(&eb2[36 + lhi8]);
    const float b3 = eb3[0];
    __syncthreads();

#pragma unroll
    for (int t = 0; t < 4; ++t) {
        const int iL = (wave << 2) + t;             // 0..31
        const unsigned int* pirow = &pi_s[iL << 6];
        const int swzI = (iL & 7) << 2;

        floatx4 acc[4];
        acc[0] = (floatx4){e0.x, e0.y, e0.z, e0.w};
        acc[1] = (floatx4){e1.x, e1.y, e1.z, e1.w};
        acc[2] = (floatx4){e2.x, e2.y, e2.z, e2.w};
        acc[3] = (floatx4){e3.x, e3.y, e3.z, e3.w};

#pragma unroll
        for (int q = 0; q < 4; ++q) {
            const int ko = (q << 4) + lhi4;         // dword offset within row
            half8v a = *reinterpret_cast<const half8v*>(&pirow[ko ^ swzI]);
            half8v b = *reinterpret_cast<const half8v*>(&pjrow[ko ^ swzJ]);
            uint4 su = __builtin_bit_cast(uint4, a + b);   // v_pk_add_f16
            uint4 gu;
            gu.x = gelu2u(su.x);
            gu.y = gelu2u(su.y);
            gu.z = gelu2u(su.z);
            gu.w = gelu2u(su.w);
            half8v af = __builtin_bit_cast(half8v, gu);    // h1 (B operand)
            const int kw = ko ^ swzJ;
#pragma unroll
            for (int c = 0; c < 4; ++c) {
                half8v bf = *reinterpret_cast<const half8v*>(
                    &w2base[(c << 10) + kw]);       // w2 slot-row c*16+lrow (A op)
                acc[c] = __builtin_amdgcn_mfma_f32_16x16x32_f16(
                    bf, af, acc[c], 0, 0, 0);       // C^T: rows=dim-slot, col=j
            }
        }

        // epilogue: h2 = gelu(acc) in f16 pairs; adj = w3-dot via second MFMA
        uint4 u0, u1;
        u0.x = gelu2u(cvt2u(acc[0][0], acc[0][1]));
        u0.y = gelu2u(cvt2u(acc[0][2], acc[0][3]));
        u0.z = gelu2u(cvt2u(acc[1][0], acc[1][1]));
        u0.w = gelu2u(cvt2u(acc[1][2], acc[1][3]));
        u1.x = gelu2u(cvt2u(acc[2][0], acc[2][1]));
        u1.y = gelu2u(cvt2u(acc[2][2], acc[2][3]));
        u1.z = gelu2u(cvt2u(acc[3][0], acc[3][1]));
        u1.w = gelu2u(cvt2u(acc[3][2], acc[3][3]));
        half8v h20 = __builtin_bit_cast(half8v, u0);   // B: k=lhi*8+e, col=j
        half8v h21 = __builtin_bit_cast(half8v, u1);   // B: k=32+lhi*8+e

        floatx4 d = (floatx4){b3, b3, b3, b3};
        d = __builtin_amdgcn_mfma_f32_16x16x32_f16(w3f0, h20, d, 0, 0, 0);
        d = __builtin_amdgcn_mfma_f32_16x16x32_f16(w3f1, h21, d, 0, 0, 0);
        // every row of D equals adj[iL][j0+lrow]; lanes lhi==0 write 16 floats
        if (lhi == 0)
            out_adj[(size_t)(i0 + iL) * KN + j0 + lrow] = d[0];
    }
}

// ---------------- Kernel C: in-place symmetrize ------------------------------
__global__ __launch_bounds__(256) void sym_kernel(float* __restrict__ adj) {
    int idx = blockIdx.x * 256 + threadIdx.x;
    int i = idx >> 10, j = idx & 1023;
    if (j < i) return;
    float a = adj[i * KN + j];
    float b = adj[j * KN + i];
    float m = 0.5f * (a + b);
    adj[i * KN + j] = m;
    adj[j * KN + i] = m;
}

extern "C" void kernel_launch(void* const* d_in, const int* in_sizes, int n_in,
                              void* d_out, int out_size, void* d_ws, size_t ws_size,
                              hipStream_t stream) {
    const float* z   = (const float*)d_in[0];
    const float* cW1 = (const float*)d_in[1];
    const float* cb1 = (const float*)d_in[2];
    const float* cW2 = (const float*)d_in[3];
    const float* cb2 = (const float*)d_in[4];
    const float* eW1 = (const float*)d_in[5];
    const float* eb1 = (const float*)d_in[6];
    const float* eW2 = (const float*)d_in[7];
    const float* eb2 = (const float*)d_in[8];
    const float* eW3 = (const float*)d_in[9];
    const float* eb3 = (const float*)d_in[10];

    float* out = (float*)d_out;
    _Float16* pi_h = (_Float16*)d_ws;            // [1024][128] f16
    _Float16* pj_h = pi_h + KN * HN;             // [1024][128] f16
    _Float16* w2T  = pj_h + KN * HN;             // [64][128]  f16 (permuted eW2^T)
    _Float16* w3h  = w2T + 64 * HN;              // [64]       f16

    prep_kernel<<<128, 256, 0, stream>>>(z, cW1, cb1, cW2, cb2, eW1, eb1, eW2,
                                         eW3, pi_h, pj_h, w2T, w3h, out);

    dim3 gridB(64, 32);   // x: 16-wide j tiles, y: 32-tall i tiles
    edge_kernel<<<gridB, 512, 0, stream>>>(pi_h, pj_h, w2T, w3h, eb2, eb3,
                                           out + 2048);

    sym_kernel<<<4096, 256, 0, stream>>>(out + 2048);
}